// Round 7
// baseline (237.799 us; speedup 1.0000x reference)
//
#include <hip/hip_runtime.h>
#include <hip/hip_bf16.h>
#include <math.h>

typedef __hip_bfloat16 bf16;
typedef __bf16 bf16x4 __attribute__((ext_vector_type(4)));
typedef __bf16 bf16x8 __attribute__((ext_vector_type(8)));
typedef float f32x4 __attribute__((ext_vector_type(4)));
typedef float f32x16 __attribute__((ext_vector_type(16)));
typedef unsigned short us4 __attribute__((ext_vector_type(4)));

#define LOG2E 1.44269504088896340736f

#if defined(__has_builtin)
#if __has_builtin(__builtin_amdgcn_exp2f)
#define EXP2(x) __builtin_amdgcn_exp2f(x)
#else
#define EXP2(x) exp2f(x)
#endif
#else
#define EXP2(x) exp2f(x)
#endif

__device__ inline __bf16 f2b(float f) {
  __hip_bfloat16 h = __float2bfloat16(f);
  return *reinterpret_cast<__bf16*>(&h);
}
__device__ inline unsigned short b2u(float f) {  // RNE scalar (cold paths)
  __hip_bfloat16 h = __float2bfloat16(f);
  return *reinterpret_cast<unsigned short*>(&h);
}
__device__ inline unsigned pk2(float a, float b) {  // packed RNE cvt (1 inst)
  __hip_bfloat162 t = __float22bfloat162_rn(make_float2(a, b));
  return *reinterpret_cast<unsigned*>(&t);
}
// 16B logical LDS read as two 8B reads (2-way-bank-friendly padded strides)
__device__ inline bf16x8 ld16(const bf16* p) {
  bf16x4 lo = *(const bf16x4*)p;
  bf16x4 hi = *(const bf16x4*)(p + 4);
  return __builtin_shufflevector(lo, hi, 0, 1, 2, 3, 4, 5, 6, 7);
}
__device__ inline void st16(bf16* p, uint4 v) {
  *(uint2*)p = make_uint2(v.x, v.y);
  *(uint2*)(p + 4) = make_uint2(v.z, v.w);
}
__device__ inline us4 shfl32_us4(us4 v) {
  uint2 u = *(uint2*)&v;
  u.x = __shfl_xor(u.x, 32);
  u.y = __shfl_xor(u.y, 32);
  return *(us4*)&u;
}
__device__ inline bf16x8 mk8(us4 lo, us4 hi) {
  bf16x4 l = *(bf16x4*)&lo;
  bf16x4 h = *(bf16x4*)&hi;
  return __builtin_shufflevector(l, h, 0, 1, 2, 3, 4, 5, 6, 7);
}
// async global->LDS, 16B/lane, lds addr = wave-uniform base + lane*16
__device__ inline void async16(const bf16* g, bf16* l) {
  __builtin_amdgcn_global_load_lds(
      (const __attribute__((address_space(1))) unsigned int*)g,
      (__attribute__((address_space(3))) unsigned int*)l, 16, 0, 0);
}

// ---------------- fused fp32 -> bf16 cast for hidden+kvs ----------------
__global__ void cast2_k(const float* __restrict__ a, const float* __restrict__ b,
                        bf16* __restrict__ oa, bf16* __restrict__ ob) {
  int gid = blockIdx.x * 256 + threadIdx.x;  // grid 4096 blocks
  const float* in = (gid < 524288) ? a : b;
  bf16* out = (gid < 524288) ? oa : ob;
  int i = (gid & 524287) * 8;
  float4 a0 = *(const float4*)(in + i);
  float4 a1 = *(const float4*)(in + i + 4);
  bf16x8 v;
  v[0] = f2b(a0.x); v[1] = f2b(a0.y); v[2] = f2b(a0.z); v[3] = f2b(a0.w);
  v[4] = f2b(a1.x); v[5] = f2b(a1.y); v[6] = f2b(a1.z); v[7] = f2b(a1.w);
  *(bf16x8*)(out + i) = v;
}

// ---------------- fused transpose + cast for all 3 weights ----------------
__global__ void transpose_all_k(const float* __restrict__ Wq, const float* __restrict__ Wkv,
                                const float* __restrict__ Wo, bf16* __restrict__ WqT,
                                bf16* __restrict__ WkvT, bf16* __restrict__ WoT) {
  __shared__ float tile[32][33];
  int z = blockIdx.z;
  const float* in = z == 0 ? Wq : (z == 1 ? Wkv : Wo);
  bf16* out = z == 0 ? WqT : (z == 1 ? WkvT : WoT);
  int cols = z == 1 ? 2048 : 1024;
  int c0 = blockIdx.x * 32;
  if (c0 >= cols) return;
  int r0 = blockIdx.y * 32;
  int tx = threadIdx.x, ty = threadIdx.y;
  for (int i = ty; i < 32; i += 8)
    tile[i][tx] = in[(size_t)(r0 + i) * cols + c0 + tx];
  __syncthreads();
  for (int i = ty; i < 32; i += 8)
    out[(size_t)(c0 + i) * 1024 + r0 + tx] = __float2bfloat16(tile[tx][i]);
}

// ---------------- T5 bias LUT (f64 bucketing = np ref), pre-scaled by log2e ----------------
__global__ void bias_lut_k(const float* __restrict__ rel_bias, float* __restrict__ lut) {
  int r = blockIdx.x * blockDim.x + threadIdx.x;
  if (r >= 4096) return;
  int rel = r - 2048;
  int b = rel > 0 ? 16 : 0;
  int ar = rel < 0 ? -rel : rel;
  int idx;
  if (ar < 8) {
    idx = b + ar;
  } else {
    double t = log((double)ar / 8.0) / log(16.0) * 8.0;
    int lg = 8 + (int)t;
    if (lg > 15) lg = 15;
    idx = b + lg;
  }
  for (int h = 0; h < 16; ++h)
    lut[h * 4096 + r] = rel_bias[idx * 16 + h] * LOG2E;
}

// ---------------- fused Q+KV projection GEMM (BK=64, XOR-swizzled LDS) ----------------
// grid (32, 24): y<8 -> Q (x log2e) -> Qb[b,h,s,d]; y>=8: gn<1024 -> Kb[b,h,k,d],
// gn>=1024 -> Vt[b,h,d,k]. Q/K use swapped-operand MFMA (D^T) for packed epilogue.
__global__ __launch_bounds__(256) void gemm_qkv_k(const bf16* __restrict__ hbf,
                                                  const bf16* __restrict__ kbf,
                                                  const bf16* __restrict__ WqT,
                                                  const bf16* __restrict__ WkvT,
                                                  bf16* __restrict__ Qb,
                                                  bf16* __restrict__ Kb,
                                                  bf16* __restrict__ Vt) {
  __shared__ __align__(16) bf16 As[128 * 64];
  __shared__ __align__(16) bf16 Bs[128 * 64];
  const int tid = threadIdx.x;
  const int lane = tid & 63;
  const int w = tid >> 6;
  const int wm = (w >> 1) * 64;
  const int wn = (w & 1) * 64;
  const int l15 = lane & 15;
  const int quad = lane >> 4;
  const int r8 = lane >> 3;            // row within 8-row segment
  const int clog = (lane & 7) ^ r8;    // swizzled source chunk

  const bool isQ = blockIdx.y < 8;
  const bf16* A = isQ ? hbf : kbf;
  const bf16* Bt = isQ ? WqT : WkvT;
  const int n0 = (isQ ? blockIdx.y : blockIdx.y - 8) * 128;
  const int m0 = blockIdx.x * 128;
  const bool isV = (!isQ) && (n0 >= 1024);

  f32x4 acc[4][4];
#pragma unroll
  for (int i = 0; i < 4; ++i)
#pragma unroll
    for (int j = 0; j < 4; ++j) acc[i][j] = (f32x4){0.f, 0.f, 0.f, 0.f};

  for (int k0 = 0; k0 < 1024; k0 += 64) {
    __syncthreads();
#pragma unroll
    for (int rep = 0; rep < 4; ++rep) {
      int seg = w * 4 + rep;  // 0..15, 8 rows each
      async16(A + (size_t)(m0 + seg * 8 + r8) * 1024 + k0 + clog * 8, As + seg * 512);
      async16(Bt + (size_t)(n0 + seg * 8 + r8) * 1024 + k0 + clog * 8, Bs + seg * 512);
    }
    __syncthreads();
#pragma unroll
    for (int kc = 0; kc < 2; ++kc) {
      bf16x8 af[4], bfr[4];
#pragma unroll
      for (int i = 0; i < 4; ++i) {
        int row = wm + i * 16 + l15;
        af[i] = *(const bf16x8*)(As + row * 64 + (((kc * 4 + quad) ^ (row & 7)) << 3));
      }
#pragma unroll
      for (int j = 0; j < 4; ++j) {
        int row = wn + j * 16 + l15;
        bfr[j] = *(const bf16x8*)(Bs + row * 64 + (((kc * 4 + quad) ^ (row & 7)) << 3));
      }
      if (isV) {
#pragma unroll
        for (int i = 0; i < 4; ++i)
#pragma unroll
          for (int j = 0; j < 4; ++j)
            acc[i][j] = __builtin_amdgcn_mfma_f32_16x16x32_bf16(af[i], bfr[j], acc[i][j], 0, 0, 0);
      } else {  // swapped: D^T for packed Q/K epilogue
#pragma unroll
        for (int i = 0; i < 4; ++i)
#pragma unroll
          for (int j = 0; j < 4; ++j)
            acc[i][j] = __builtin_amdgcn_mfma_f32_16x16x32_bf16(bfr[j], af[i], acc[i][j], 0, 0, 0);
      }
    }
  }

  if (isV) {  // V -> [b,h,d,k], 4 consecutive k per 8B store
#pragma unroll
    for (int i = 0; i < 4; ++i) {
      int gmb = m0 + wm + i * 16 + quad * 4;
      int b = gmb >> 11, kp = gmb & 2047;
#pragma unroll
      for (int j = 0; j < 4; ++j) {
        int gn = n0 + wn + j * 16 + l15;
        int h = (gn >> 6) & 15, d = gn & 63;
        uint2 u;
        u.x = pk2(acc[i][j][0], acc[i][j][1]);
        u.y = pk2(acc[i][j][2], acc[i][j][3]);
        *(uint2*)(Vt + ((((size_t)b * 16 + h) * 64 + d) << 11) + kp) = u;
      }
    }
    return;
  }
  // Q/K swapped epilogue: gm = ..+l15 (s), gn = ..+quad*4+r (d packed)
  const float scale = isQ ? LOG2E : 1.0f;
  bf16* dst = isQ ? Qb : Kb;
#pragma unroll
  for (int i = 0; i < 4; ++i) {
    int gm = m0 + wm + i * 16 + l15;
    int b = gm >> 11, s = gm & 2047;
#pragma unroll
    for (int j = 0; j < 4; ++j) {
      int gn = n0 + wn + j * 16 + quad * 4;
      int h = (gn >> 6) & 15, d0 = gn & 63;
      uint2 u;
      u.x = pk2(acc[i][j][0] * scale, acc[i][j][1] * scale);
      u.y = pk2(acc[i][j][2] * scale, acc[i][j][3] * scale);
      *(uint2*)(dst + ((((size_t)b * 16 + h) * 2048 + s) << 6) + d0) = u;
    }
  }
}

// ---------------- O projection (BK=64, swizzled): out = Ob * WoT^T, 128x64 tiles ----------------
__global__ __launch_bounds__(256) void gemm_o_k(const bf16* __restrict__ A,
                                                const bf16* __restrict__ Bt,
                                                float* __restrict__ C0) {
  __shared__ __align__(16) bf16 As[128 * 64];
  __shared__ __align__(16) bf16 Bs[64 * 64];
  const int tid = threadIdx.x;
  const int lane = tid & 63;
  const int w = tid >> 6;
  const int wm = w * 32;
  const int m0 = blockIdx.x * 128;
  const int n0 = blockIdx.y * 64;
  const int l15 = lane & 15;
  const int quad = lane >> 4;
  const int r8 = lane >> 3;
  const int clog = (lane & 7) ^ r8;

  f32x4 acc[2][4];
#pragma unroll
  for (int i = 0; i < 2; ++i)
#pragma unroll
    for (int j = 0; j < 4; ++j) acc[i][j] = (f32x4){0.f, 0.f, 0.f, 0.f};

  for (int k0 = 0; k0 < 1024; k0 += 64) {
    __syncthreads();
#pragma unroll
    for (int rep = 0; rep < 4; ++rep) {
      int seg = w * 4 + rep;
      async16(A + (size_t)(m0 + seg * 8 + r8) * 1024 + k0 + clog * 8, As + seg * 512);
    }
#pragma unroll
    for (int rep = 0; rep < 2; ++rep) {
      int seg = w * 2 + rep;  // 0..7
      async16(Bt + (size_t)(n0 + seg * 8 + r8) * 1024 + k0 + clog * 8, Bs + seg * 512);
    }
    __syncthreads();
#pragma unroll
    for (int kc = 0; kc < 2; ++kc) {
      bf16x8 af[2], bfr[4];
#pragma unroll
      for (int i = 0; i < 2; ++i) {
        int row = wm + i * 16 + l15;
        af[i] = *(const bf16x8*)(As + row * 64 + (((kc * 4 + quad) ^ (row & 7)) << 3));
      }
#pragma unroll
      for (int j = 0; j < 4; ++j) {
        int row = j * 16 + l15;
        bfr[j] = *(const bf16x8*)(Bs + row * 64 + (((kc * 4 + quad) ^ (row & 7)) << 3));
      }
#pragma unroll
      for (int i = 0; i < 2; ++i)
#pragma unroll
        for (int j = 0; j < 4; ++j)
          acc[i][j] = __builtin_amdgcn_mfma_f32_16x16x32_bf16(bfr[j], af[i], acc[i][j], 0, 0, 0);
    }
  }
#pragma unroll
  for (int i = 0; i < 2; ++i) {
    int gm = m0 + wm + i * 16 + l15;
#pragma unroll
    for (int j = 0; j < 4; ++j) {
      int gn = n0 + j * 16 + quad * 4;
      *(f32x4*)(C0 + (size_t)gm * 1024 + gn) = acc[i][j];
    }
  }
}

// ---------------- fused attention: transposed-S, fixed-ref softmax, far-bias path ----------------
// grid (16, 32), 4 waves; wave w owns q-strip [qb+w*32,+32); lane owns one q (col=lane&31)
// Scores bounded (|s*log2e| << 127) -> no online max needed: p = exp2(s+bias), l = sum p.
// T5 buckets saturate at |rel|>=91 -> off-band tiles use a register bias constant.
#define STK 68
#define SVK 136
__global__ __launch_bounds__(256) void attn_k(const bf16* __restrict__ Qb,
                                              const bf16* __restrict__ Kb,
                                              const bf16* __restrict__ Vt,
                                              const float* __restrict__ lut,
                                              bf16* __restrict__ Ob) {
  __shared__ float lbias[2176];
  __shared__ __align__(16) bf16 Ks[128 * STK];  // [k][d]
  __shared__ __align__(16) bf16 Vs[64 * SVK];   // [d][k]

  const int tid = threadIdx.x;
  const int lane = tid & 63;
  const int w = tid >> 6;
  const int q31 = lane & 31;
  const int half = lane >> 5;

  const int qt = blockIdx.x;  // 0..15
  const int bh = blockIdx.y;  // 0..31
  const int h = bh & 15, b = bh >> 4;
  const int qb = qt * 128;

  const int gbase = h * 4096 + 1921 - qb;
  for (int t = tid; t < 2175; t += 256) lbias[t] = lut[gbase + t];

  const float c_pos = lut[h * 4096 + 2048 + 120];  // bucket saturated, rel >= 91
  const float c_neg = lut[h * 4096 + 2048 - 120];  // bucket saturated, rel <= -91

  const size_t base = (size_t)bh * 2048 * 64;   // Qb/Kb rows
  const size_t vbase = (size_t)bh * 64 * 2048;  // Vt rows
  const int qg = qb + w * 32 + q31;

  // Q B-frags (pre-scaled by log2e in projection)
  bf16x8 qf[4];
#pragma unroll
  for (int c = 0; c < 4; ++c)
    qf[c] = *(const bf16x8*)(Qb + base + (size_t)qg * 64 + c * 16 + half * 8);

  f32x16 oacc[2];
#pragma unroll
  for (int dj = 0; dj < 2; ++dj)
#pragma unroll
    for (int r = 0; r < 16; ++r) oacc[dj][r] = 0.f;
  float l_run = 0.f;

  // prefetch tile 0 staging into registers
  uint4 kreg[4], vreg[4];
#pragma unroll
  for (int rep = 0; rep < 4; ++rep) {
    int slot = tid + rep * 256;
    kreg[rep] = *(const uint4*)(Kb + base + (size_t)(slot >> 3) * 64 + (slot & 7) * 8);
    vreg[rep] = *(const uint4*)(Vt + vbase + (size_t)(slot >> 4) * 2048 + (slot & 15) * 8);
  }

  for (int kt = 0; kt < 2048; kt += 128) {
    __syncthreads();  // all waves done reading Ks/Vs
#pragma unroll
    for (int rep = 0; rep < 4; ++rep) {
      int slot = tid + rep * 256;
      st16(Ks + (slot >> 3) * STK + (slot & 7) * 8, kreg[rep]);
      st16(Vs + (slot >> 4) * SVK + (slot & 15) * 8, vreg[rep]);
    }
    __syncthreads();
    if (kt + 128 < 2048) {  // prefetch next tile; latency hides behind compute
#pragma unroll
      for (int rep = 0; rep < 4; ++rep) {
        int slot = tid + rep * 256;
        kreg[rep] = *(const uint4*)(Kb + base + (size_t)(kt + 128 + (slot >> 3)) * 64 + (slot & 7) * 8);
        vreg[rep] = *(const uint4*)(Vt + vbase + (size_t)(slot >> 4) * 2048 + kt + 128 + (slot & 15) * 8);
      }
    }

    // S^T = K·Q^T : 4 k-Mtiles, contraction over d (4 chunks)
    f32x16 sacc[4];
#pragma unroll
    for (int mt = 0; mt < 4; ++mt) {
#pragma unroll
      for (int r = 0; r < 16; ++r) sacc[mt][r] = 0.f;
#pragma unroll
      for (int c = 0; c < 4; ++c) {
        bf16x8 kf = ld16(Ks + (mt * 32 + q31) * STK + c * 16 + half * 8);
        sacc[mt] = __builtin_amdgcn_mfma_f32_32x32x16_bf16(kf, qf[c], sacc[mt], 0, 0, 0);
      }
    }

    // bias + exp (no max subtraction needed: scores bounded)
    bool farp = (kt - qg) >= 91;
    bool farn = (qg - (kt + 127)) >= 91;
    float sum0 = 0.f, sum1 = 0.f;
    if (__ballot(farp | farn) == 0xFFFFFFFFFFFFFFFFull) {
      float cb = farp ? c_pos : c_neg;
#pragma unroll
      for (int mt = 0; mt < 4; ++mt)
#pragma unroll
        for (int r = 0; r < 16; ++r) {
          float p = EXP2(sacc[mt][r] + cb);
          sacc[mt][r] = p;
          if (r & 1) sum1 += p; else sum0 += p;
        }
    } else {
      const int xbase = kt + 127 + 4 * half - w * 32 - q31;
#pragma unroll
      for (int mt = 0; mt < 4; ++mt)
#pragma unroll
        for (int g = 0; g < 4; ++g) {
          int x0 = xbase + mt * 32 + 8 * g;
#pragma unroll
          for (int rr = 0; rr < 4; ++rr) {
            float p = EXP2(sacc[mt][4 * g + rr] + lbias[x0 + rr]);
            sacc[mt][4 * g + rr] = p;
            if (rr & 1) sum1 += p; else sum0 += p;
          }
        }
    }
    float sum = sum0 + sum1;
    sum += __shfl_xor(sum, 32);
    l_run += sum;

    // pack P quads (packed RNE cvt) and exchange across half boundary
    us4 ownq[4][4], rcv[4][2];
#pragma unroll
    for (int mt = 0; mt < 4; ++mt) {
#pragma unroll
      for (int a = 0; a < 4; ++a) {
        uint2 u;
        u.x = pk2(sacc[mt][4 * a + 0], sacc[mt][4 * a + 1]);
        u.y = pk2(sacc[mt][4 * a + 2], sacc[mt][4 * a + 3]);
        ownq[mt][a] = *(us4*)&u;
      }
      us4 s0 = half ? ownq[mt][0] : ownq[mt][1];
      us4 s1 = half ? ownq[mt][2] : ownq[mt][3];
      rcv[mt][0] = shfl32_us4(s0);
      rcv[mt][1] = shfl32_us4(s1);
    }

    // O^T += V^T·P^T (no rescale: fixed reference)
#pragma unroll
    for (int c = 0; c < 8; ++c) {
      int mt = c >> 1, p = c & 1;
      bf16x8 pfc = half ? mk8(rcv[mt][p], ownq[mt][2 * p + 1])
                        : mk8(ownq[mt][2 * p], rcv[mt][p]);
#pragma unroll
      for (int dj = 0; dj < 2; ++dj) {
        bf16x8 vf = ld16(Vs + (dj * 32 + q31) * SVK + c * 16 + half * 8);
        oacc[dj] = __builtin_amdgcn_mfma_f32_32x32x16_bf16(vf, pfc, oacc[dj], 0, 0, 0);
      }
    }
  }

  // epilogue: O[qg][d] = O^T/l, 8B packed stores
  float inv = 1.0f / l_run;
#pragma unroll
  for (int dj = 0; dj < 2; ++dj)
#pragma unroll
    for (int g = 0; g < 4; ++g) {
      uint2 u;
      u.x = pk2(oacc[dj][4 * g + 0] * inv, oacc[dj][4 * g + 1] * inv);
      u.y = pk2(oacc[dj][4 * g + 2] * inv, oacc[dj][4 * g + 3] * inv);
      int d0 = dj * 32 + 8 * g + 4 * half;
      *(uint2*)(Ob + ((size_t)(b * 2048 + qg)) * 1024 + h * 64 + d0) = u;
    }
}

// ---------------- launch ----------------
extern "C" void kernel_launch(void* const* d_in, const int* in_sizes, int n_in,
                              void* d_out, int out_size, void* d_ws, size_t ws_size,
                              hipStream_t stream) {
  const float* hidden = (const float*)d_in[0];
  const float* kvs    = (const float*)d_in[1];
  const float* Wq     = (const float*)d_in[2];
  const float* Wkv    = (const float*)d_in[3];
  const float* Wo     = (const float*)d_in[4];
  const float* relb   = (const float*)d_in[5];
  float* out = (float*)d_out;

  char* ws = (char*)d_ws;
  bf16* WqT  = (bf16*)(ws + (size_t)0);           // 2 MB
  bf16* WkvT = (bf16*)(ws + ((size_t)2 << 20));   // 4 MB
  bf16* WoT  = (bf16*)(ws + ((size_t)6 << 20));   // 2 MB
  bf16* Ob   = (bf16*)(ws + ((size_t)8 << 20));   // 8 MB [B,S,E]
  bf16* hbf  = Ob;                                //   aliased: dead after gemm_qkv
  bf16* Qb   = (bf16*)(ws + ((size_t)16 << 20));  // 8 MB [B,H,S,D]
  bf16* Kb   = (bf16*)(ws + ((size_t)24 << 20));  // 8 MB [B,H,K,D]
  bf16* Vt   = (bf16*)(ws + ((size_t)32 << 20));  // 8 MB [B,H,D,K]
  float* LUT = (float*)(ws + ((size_t)40 << 20)); // 256 KB
  bf16* kbf  = (bf16*)d_out;                      // 8 MB scratch in d_out, overwritten by gemm_o

  transpose_all_k<<<dim3(64, 32, 3), dim3(32, 8), 0, stream>>>(Wq, Wkv, Wo, WqT, WkvT, WoT);
  bias_lut_k<<<16, 256, 0, stream>>>(relb, LUT);
  cast2_k<<<4096, 256, 0, stream>>>(hidden, kvs, hbf, kbf);

  // Q (x log2e), K, V projections
  gemm_qkv_k<<<dim3(32, 24), 256, 0, stream>>>(hbf, kbf, WqT, WkvT, Qb, Kb, Vt);
  // attention -> Ob (overwrites hbf region, safe: hbf consumed)
  attn_k<<<dim3(16, 32), 256, 0, stream>>>(Qb, Kb, Vt, LUT, Ob);
  // out = Ob @ Wo (overwrites kbf region, safe: kbf consumed)
  gemm_o_k<<<dim3(32, 16), 256, 0, stream>>>(Ob, WoT, out);
}